// Round 4
// baseline (240.300 us; speedup 1.0000x reference)
//
#include <hip/hip_runtime.h>
#include <math.h>

// Problem constants (from setup_inputs)
#define T_TOTAL 2097152
#define A_DIM   18
#define GAMMA_D 0.99

#define CHUNK 256
#define NC    (T_TOTAL / CHUNK)        // 8192 chunks
#define KTR   14                       // G^14 ~ 2e-16, G = 0.99^256 ~ 0.076
#define NB_MAIN 4096                   // k_main: 256 thr x 2 rows = 512 rows/blk

// ---------------------------------------------------------------------------
// Kernel A: per-chunk local discounted sums, one WAVE per chunk.
// L[c] = sum_{j=0}^{255} g^j r[c*256+j]
__global__ void k_local(const float* __restrict__ r, double* __restrict__ L) {
    const int tid  = blockIdx.x * blockDim.x + threadIdx.x;
    const int c    = tid >> 6;
    const int lane = tid & 63;
    const float4 v = ((const float4*)r)[(size_t)c * 64 + lane];
    const double g = GAMMA_D;
    double w = pow(g, (double)(4 * lane)) *
               ((double)v.x + g * ((double)v.y + g * ((double)v.z + g * (double)v.w)));
    #pragma unroll
    for (int off = 32; off > 0; off >>= 1) w += __shfl_down(w, off, 64);
    if (lane == 0) L[c] = w;
}

// ---------------------------------------------------------------------------
// Kernel B: materialize d[t] for all t. One wave per chunk; lane owns 4
// consecutive rows. carry computed inline from L (64 KiB, L2-resident,
// wave-uniform loads -> s_load). Removes the scan from the hot kernel.
__global__ __launch_bounds__(256)
void k_d(const float* __restrict__ r, const double* __restrict__ L,
         double* __restrict__ d) {
    const int tid = threadIdx.x, lane = tid & 63, wv = tid >> 6;
    const int c = blockIdx.x * 4 + wv;
    const double g  = GAMMA_D;
    const double G_ = pow(g, 256.0);
    // carry for this chunk: sum_{m=0}^{13} G^m L[c+1+m]
    double acc = 0.0, wG = 1.0;
    #pragma unroll
    for (int m = 0; m < KTR; ++m) {
        const int idx = c + 1 + m;
        if (idx < NC) acc += wG * L[idx];
        wG *= G_;
    }
    // per-lane suffix over its 4 rows (f64)
    const float4 v = ((const float4*)r)[(size_t)c * 64 + lane];
    const double u3 = (double)v.w;
    const double u2 = (double)v.z + g * u3;
    const double u1 = (double)v.y + g * u2;
    const double u0 = (double)v.x + g * u1;
    // inclusive suffix-scan over lanes of t_l = g^{4l} * u0
    const double w4 = pow(g, (double)(4 * lane));
    double S = w4 * u0;
    #pragma unroll
    for (int off = 1; off < 64; off <<= 1) {
        const double t = __shfl_down(S, off, 64);
        S += (lane + off < 64) ? t : 0.0;
    }
    double Snext = __shfl_down(S, 1, 64);      // sum over lanes > l
    if (lane == 63) Snext = 0.0;
    // d[4l+j] = u_j + g^{-(4l+j)} * (Snext + G_*carry)
    const double A  = (1.0 / w4) * (Snext + G_ * acc);   // |1/w4| <= ~12.7
    const double ig = 1.0 / g;
    const double d0 = u0 + A;
    const double d1 = u1 + ig * A;
    const double d2 = u2 + (ig * ig) * A;
    const double d3 = u3 + (ig * ig * ig) * A;
    double2* dp = (double2*)(d + (size_t)c * CHUNK + 4 * lane);
    dp[0] = make_double2(d0, d1);
    dp[1] = make_double2(d2, d3);
}

// ---------------------------------------------------------------------------
// Kernel C: pure streaming. No LDS tile, no barriers, no scan.
// Thread owns 2 consecutive rows: 9x float4 (144 B, 16B-aligned), d as
// double2, act as int2. logsumexp entirely in registers; act-gather via
// compile-time-indexed cndmask chain (no dynamic register indexing).
__global__ __launch_bounds__(256, 4)
void k_main(const float* __restrict__ wgt, const int* __restrict__ act,
            const double* __restrict__ dret, double* __restrict__ partials) {
    __shared__ double red[12];
    const int tid  = threadIdx.x;
    const int lane = tid & 63, wv = tid >> 6;
    const size_t t0 = ((size_t)blockIdx.x * 256 + tid) * 2;

    const float4* wp = (const float4*)(wgt + t0 * A_DIM);
    float w[36];
    #pragma unroll
    for (int q = 0; q < 9; ++q) {
        const float4 v = wp[q];
        w[4*q+0] = v.x; w[4*q+1] = v.y; w[4*q+2] = v.z; w[4*q+3] = v.w;
    }
    const int2    aa = *(const int2*)(act + t0);
    const double2 dd = *(const double2*)(dret + t0);

    double s_n = 0.0, s_nd = 0.0;
    double s_d = dd.x + dd.y;
    {   // row 0  (exact op order preserved from verified kernel)
        float mx = w[0];
        #pragma unroll
        for (int j = 1; j < A_DIM; ++j) mx = fmaxf(mx, w[j]);
        float s = 0.0f, wsel = 0.0f;
        #pragma unroll
        for (int j = 0; j < A_DIM; ++j) {
            s += expf(w[j] - mx);
            wsel = (j == aa.x) ? w[j] : wsel;
        }
        const float nlp = mx + logf(s) - wsel;
        s_n += (double)nlp;  s_nd += (double)nlp * dd.x;
    }
    {   // row 1
        float mx = w[18];
        #pragma unroll
        for (int j = 1; j < A_DIM; ++j) mx = fmaxf(mx, w[18 + j]);
        float s = 0.0f, wsel = 0.0f;
        #pragma unroll
        for (int j = 0; j < A_DIM; ++j) {
            s += expf(w[18 + j] - mx);
            wsel = (j == aa.y) ? w[18 + j] : wsel;
        }
        const float nlp = mx + logf(s) - wsel;
        s_n += (double)nlp;  s_nd += (double)nlp * dd.y;
    }

    // block reduction: 64-lane shuffles, then cross-wave via LDS
    #pragma unroll
    for (int off = 32; off > 0; off >>= 1) {
        s_d  += __shfl_down(s_d,  off, 64);
        s_n  += __shfl_down(s_n,  off, 64);
        s_nd += __shfl_down(s_nd, off, 64);
    }
    if (lane == 0) { red[wv*3+0] = s_d; red[wv*3+1] = s_n; red[wv*3+2] = s_nd; }
    __syncthreads();
    if (tid == 0) {
        double a = 0.0, b = 0.0, cc = 0.0;
        #pragma unroll
        for (int q = 0; q < 4; ++q) { a += red[q*3]; b += red[q*3+1]; cc += red[q*3+2]; }
        partials[blockIdx.x*3+0] = a;
        partials[blockIdx.x*3+1] = b;
        partials[blockIdx.x*3+2] = cc;
    }
}

// ---------------------------------------------------------------------------
// Kernel D: reduce per-block partials, finalize scalar.
__global__ void k_final(const double* __restrict__ partials, float* __restrict__ out) {
    __shared__ double red[12];
    const int tid = threadIdx.x;
    double a = 0.0, b = 0.0, c = 0.0;
    for (int i = tid; i < NB_MAIN; i += 256) {
        a += partials[i*3+0];
        b += partials[i*3+1];
        c += partials[i*3+2];
    }
    #pragma unroll
    for (int off = 32; off > 0; off >>= 1) {
        a += __shfl_down(a, off, 64);
        b += __shfl_down(b, off, 64);
        c += __shfl_down(c, off, 64);
    }
    const int lane = tid & 63, wv = tid >> 6;
    if (lane == 0) { red[wv*3+0] = a; red[wv*3+1] = b; red[wv*3+2] = c; }
    __syncthreads();
    if (tid == 0) {
        double A_ = 0.0, B_ = 0.0, C_ = 0.0;
        #pragma unroll
        for (int i = 0; i < 4; ++i) { A_ += red[i*3]; B_ += red[i*3+1]; C_ += red[i*3+2]; }
        const double invT = 1.0 / (double)T_TOTAL;
        // out = (1/T) * ( sum(nlp*d) - mean(d) * sum(nlp) )
        out[0] = (float)((C_ - (A_ * invT) * B_) * invT);
    }
}

// ---------------------------------------------------------------------------
extern "C" void kernel_launch(void* const* d_in, const int* in_sizes, int n_in,
                              void* d_out, int out_size, void* d_ws, size_t ws_size,
                              hipStream_t stream) {
    const float* weight = (const float*)d_in[0];   // [T, 18] f32
    const float* ep_rs  = (const float*)d_in[1];   // [T] f32
    const int*   ep_as  = (const int*)  d_in[2];   // [T] int
    float* out = (float*)d_out;

    char* ws = (char*)d_ws;
    double* L        = (double*)(ws);                          // 64 KiB
    double* dret     = (double*)(ws + (1 << 16));              // 16 MiB
    double* partials = (double*)(ws + (1 << 16) + (16 << 20)); // 96 KiB

    k_local <<<T_TOTAL / 4 / 256, 256, 0, stream>>>(ep_rs, L);     // 2048 blocks
    k_d     <<<NC / 4,            256, 0, stream>>>(ep_rs, L, dret); // 2048 blocks
    k_main  <<<NB_MAIN,           256, 0, stream>>>(weight, ep_as, dret, partials);
    k_final <<<1,                 256, 0, stream>>>(partials, out);
}

// Round 5
// 232.639 us; speedup vs baseline: 1.0329x; 1.0329x over previous
//
#include <hip/hip_runtime.h>
#include <math.h>

// Problem constants (from setup_inputs)
#define T_TOTAL 2097152
#define A_DIM   18
#define GAMMA_D 0.99

#define CHUNK 256
#define NC    (T_TOTAL / CHUNK)        // 8192 chunks
#define KTR   14                       // G^14 ~ 2e-16, G = 0.99^256 ~ 0.076
#define CPB   4                        // chunks per block
#define NB    (NC / CPB)               // 2048 blocks

// ---------------------------------------------------------------------------
// Fused mega-kernel: block b owns chunks [4b, 4b+3] = rows [1024b, 1024b+1023].
//  phase 0: issue pair-0 weight loads (registers) so HBM streaming starts now
//  phase 1: window L[c0+1 .. c0+17] recomputed from ep_rs (one wave-chunk each)
//  phase 2: per-wave own-chunk d via lane-suffix scan (k_d logic, bit-exact),
//           d -> 8 KB LDS
//  phase 3: per-thread 2 row-pairs: register logsumexp, accumulate
//           {sum d, sum nlp, sum nlp*d} in f64, block-reduce, one partial-triple
// No dret round-trip, no k_local/k_d kernels, 1 dependency edge total.
__global__ __launch_bounds__(256, 4)
void k_mega(const float* __restrict__ wgt, const int* __restrict__ act,
            const float* __restrict__ r, double* __restrict__ partials) {
    __shared__ double ldsL[17];               // window chunk-sums
    __shared__ double ldsD[CPB * CHUNK];      // d for the block's 1024 rows (8 KB)
    __shared__ double red[12];
    const int tid  = threadIdx.x;
    const int lane = tid & 63, wv = tid >> 6;
    const int c0   = blockIdx.x * CPB;
    const double g  = GAMMA_D;
    const double G_ = pow(g, 256.0);
    const double w4 = pow(g, (double)(4 * lane));

    // ---- phase 0: issue pair-0 weight/act loads early ----
    const size_t rowBase = (size_t)c0 * CHUNK;
    const float4* wp0 = (const float4*)(wgt + (rowBase + 2 * (size_t)tid) * A_DIM);
    float4 a0[9];
    #pragma unroll
    for (int q = 0; q < 9; ++q) a0[q] = wp0[q];
    const int2 aa0 = *(const int2*)(act + rowBase + 2 * tid);

    // ---- phase 1: window L (wave wv handles k = wv, wv+4, ...) ----
    #pragma unroll
    for (int i = 0; i < 5; ++i) {
        const int k  = wv + 4 * i;
        const int cc = c0 + 1 + k;
        if (k < 17) {
            double val = 0.0;
            if (cc < NC) {                    // wave-uniform guard
                const float4 v = ((const float4*)r)[(size_t)cc * 64 + lane];
                val = w4 * ((double)v.x + g * ((double)v.y + g * ((double)v.z + g * (double)v.w)));
                #pragma unroll
                for (int off = 32; off > 0; off >>= 1) val += __shfl_down(val, off, 64);
            }
            if (lane == 0) ldsL[k] = val;
        }
    }
    __syncthreads();

    // ---- phase 2: own-chunk d (wave wv -> chunk c0+wv), k_d logic verbatim ----
    {
        // carry for chunk c0+wv: sum_{m=0}^{13} G^m L[c0+wv+1+m]  (wv+13 <= 16)
        double acc = 0.0, wG = 1.0;
        #pragma unroll
        for (int m = 0; m < KTR; ++m) { acc += wG * ldsL[wv + m]; wG *= G_; }
        const int c = c0 + wv;
        const float4 v = ((const float4*)r)[(size_t)c * 64 + lane];
        const double u3 = (double)v.w;
        const double u2 = (double)v.z + g * u3;
        const double u1 = (double)v.y + g * u2;
        const double u0 = (double)v.x + g * u1;
        double S = w4 * u0;
        #pragma unroll
        for (int off = 1; off < 64; off <<= 1) {
            const double t = __shfl_down(S, off, 64);
            S += (lane + off < 64) ? t : 0.0;
        }
        double Snext = __shfl_down(S, 1, 64);
        if (lane == 63) Snext = 0.0;
        const double A  = (1.0 / w4) * (Snext + G_ * acc);
        const double ig = 1.0 / g;
        double* dp = ldsD + wv * CHUNK + 4 * lane;
        dp[0] = u0 + A;
        dp[1] = u1 + ig * A;
        dp[2] = u2 + (ig * ig) * A;
        dp[3] = u3 + (ig * ig * ig) * A;
    }
    __syncthreads();

    // ---- phase 3: logsumexp on two row-pairs ----
    // issue pair-1 loads first so they overlap pair-0 compute
    const float4* wp1 = (const float4*)(wgt + (rowBase + 512 + 2 * (size_t)tid) * A_DIM);
    float4 a1[9];
    #pragma unroll
    for (int q = 0; q < 9; ++q) a1[q] = wp1[q];
    const int2    aa1 = *(const int2*)(act + rowBase + 512 + 2 * tid);
    const double2 dd0 = *(const double2*)(ldsD + 2 * tid);        // conflict-free
    const double2 dd1 = *(const double2*)(ldsD + 512 + 2 * tid);

    double s_n = 0.0, s_nd = 0.0;
    double s_d = dd0.x + dd0.y + dd1.x + dd1.y;
    float w[36];
    // pair 0
    #pragma unroll
    for (int q = 0; q < 9; ++q) {
        w[4*q+0] = a0[q].x; w[4*q+1] = a0[q].y; w[4*q+2] = a0[q].z; w[4*q+3] = a0[q].w;
    }
    {   // row 0 (exact op order preserved)
        float mx = w[0];
        #pragma unroll
        for (int j = 1; j < A_DIM; ++j) mx = fmaxf(mx, w[j]);
        float s = 0.0f, wsel = 0.0f;
        #pragma unroll
        for (int j = 0; j < A_DIM; ++j) { s += expf(w[j] - mx); wsel = (j == aa0.x) ? w[j] : wsel; }
        const float nlp = mx + logf(s) - wsel;
        s_n += (double)nlp;  s_nd += (double)nlp * dd0.x;
    }
    {   // row 1
        float mx = w[18];
        #pragma unroll
        for (int j = 1; j < A_DIM; ++j) mx = fmaxf(mx, w[18 + j]);
        float s = 0.0f, wsel = 0.0f;
        #pragma unroll
        for (int j = 0; j < A_DIM; ++j) { s += expf(w[18 + j] - mx); wsel = (j == aa0.y) ? w[18 + j] : wsel; }
        const float nlp = mx + logf(s) - wsel;
        s_n += (double)nlp;  s_nd += (double)nlp * dd0.y;
    }
    // pair 1
    #pragma unroll
    for (int q = 0; q < 9; ++q) {
        w[4*q+0] = a1[q].x; w[4*q+1] = a1[q].y; w[4*q+2] = a1[q].z; w[4*q+3] = a1[q].w;
    }
    {   // row 2
        float mx = w[0];
        #pragma unroll
        for (int j = 1; j < A_DIM; ++j) mx = fmaxf(mx, w[j]);
        float s = 0.0f, wsel = 0.0f;
        #pragma unroll
        for (int j = 0; j < A_DIM; ++j) { s += expf(w[j] - mx); wsel = (j == aa1.x) ? w[j] : wsel; }
        const float nlp = mx + logf(s) - wsel;
        s_n += (double)nlp;  s_nd += (double)nlp * dd1.x;
    }
    {   // row 3
        float mx = w[18];
        #pragma unroll
        for (int j = 1; j < A_DIM; ++j) mx = fmaxf(mx, w[18 + j]);
        float s = 0.0f, wsel = 0.0f;
        #pragma unroll
        for (int j = 0; j < A_DIM; ++j) { s += expf(w[18 + j] - mx); wsel = (j == aa1.y) ? w[18 + j] : wsel; }
        const float nlp = mx + logf(s) - wsel;
        s_n += (double)nlp;  s_nd += (double)nlp * dd1.y;
    }

    // block reduction
    #pragma unroll
    for (int off = 32; off > 0; off >>= 1) {
        s_d  += __shfl_down(s_d,  off, 64);
        s_n  += __shfl_down(s_n,  off, 64);
        s_nd += __shfl_down(s_nd, off, 64);
    }
    if (lane == 0) { red[wv*3+0] = s_d; red[wv*3+1] = s_n; red[wv*3+2] = s_nd; }
    __syncthreads();
    if (tid == 0) {
        double a = 0.0, b = 0.0, cc = 0.0;
        #pragma unroll
        for (int q = 0; q < 4; ++q) { a += red[q*3]; b += red[q*3+1]; cc += red[q*3+2]; }
        partials[blockIdx.x*3+0] = a;
        partials[blockIdx.x*3+1] = b;
        partials[blockIdx.x*3+2] = cc;
    }
}

// ---------------------------------------------------------------------------
// Final reduce: per-block partials -> scalar.
__global__ void k_final(const double* __restrict__ partials, float* __restrict__ out) {
    __shared__ double red[12];
    const int tid = threadIdx.x;
    double a = 0.0, b = 0.0, c = 0.0;
    for (int i = tid; i < NB; i += 256) {
        a += partials[i*3+0];
        b += partials[i*3+1];
        c += partials[i*3+2];
    }
    #pragma unroll
    for (int off = 32; off > 0; off >>= 1) {
        a += __shfl_down(a, off, 64);
        b += __shfl_down(b, off, 64);
        c += __shfl_down(c, off, 64);
    }
    const int lane = tid & 63, wv = tid >> 6;
    if (lane == 0) { red[wv*3+0] = a; red[wv*3+1] = b; red[wv*3+2] = c; }
    __syncthreads();
    if (tid == 0) {
        double A_ = 0.0, B_ = 0.0, C_ = 0.0;
        #pragma unroll
        for (int i = 0; i < 4; ++i) { A_ += red[i*3]; B_ += red[i*3+1]; C_ += red[i*3+2]; }
        const double invT = 1.0 / (double)T_TOTAL;
        // out = (1/T) * ( sum(nlp*d) - mean(d) * sum(nlp) )
        out[0] = (float)((C_ - (A_ * invT) * B_) * invT);
    }
}

// ---------------------------------------------------------------------------
extern "C" void kernel_launch(void* const* d_in, const int* in_sizes, int n_in,
                              void* d_out, int out_size, void* d_ws, size_t ws_size,
                              hipStream_t stream) {
    const float* weight = (const float*)d_in[0];   // [T, 18] f32
    const float* ep_rs  = (const float*)d_in[1];   // [T] f32
    const int*   ep_as  = (const int*)  d_in[2];   // [T] int
    float* out = (float*)d_out;

    double* partials = (double*)d_ws;              // NB*3 doubles (48 KiB)

    k_mega  <<<NB, 256, 0, stream>>>(weight, ep_as, ep_rs, partials);
    k_final <<<1,  256, 0, stream>>>(partials, out);
}